// Round 3
// baseline (436.186 us; speedup 1.0000x reference)
//
#include <hip/hip_runtime.h>

#define SLOPE 0.01f

typedef float f32x4 __attribute__((ext_vector_type(4)));

// Weight pointers passed by value in the kernarg segment (160 B). The layer
// loop is fully unrolled -> h.w[L]/h.b[L] are compile-time kernarg offsets ->
// uniform pointers -> weights become scalar (s_load) broadcast operands.
struct Half5 { const float* w[5]; const float* b[5]; };
struct WPtrs { Half5 logs; Half5 aff; };

// 5-layer 8->8 MLP, leaky ReLU after first 4 layers.
// w[L]: 64 fp32 row-major (out[j] += w[j*8+k] * x[k]); b[L]: 8 fp32.
__device__ __forceinline__ void mlp8(const Half5& h, const float x[8], float out[8]) {
    float a[8];
    #pragma unroll
    for (int j = 0; j < 8; ++j) a[j] = x[j];
    #pragma unroll
    for (int L = 0; L < 5; ++L) {
        const float* __restrict__ wl = h.w[L];
        const float* __restrict__ bl = h.b[L];
        float t[8];
        #pragma unroll
        for (int j = 0; j < 8; ++j) {
            float acc = bl[j];
            #pragma unroll
            for (int k = 0; k < 8; ++k)
                acc = fmaf(wl[j * 8 + k], a[k], acc);
            t[j] = acc;
        }
        #pragma unroll
        for (int j = 0; j < 8; ++j)
            a[j] = (L < 4) ? fmaxf(t[j], SLOPE * t[j]) : t[j];
    }
    #pragma unroll
    for (int j = 0; j < 8; ++j) out[j] = a[j];
}

// Memory pattern rationale (measured across 3 rounds on this problem):
//  - Plain (non-nt) strided float4 loads/stores: kernel ~85-100 us. A wave's
//    4 store instructions each write 16 B into 64 distinct lines, but L2
//    merges them into full 64 B lines before eviction -> WRITE_SIZE clean.
//  - Adding nontemporal to these stores bypasses that merge -> 1.5x HBM
//    write amplification (R1: WRITE_SIZE 384 MB vs 256 MB, kernel 224 us).
//  - LDS corner-turn with nt both sides: coalesced but ~115 us (LDS ops +
//    serial per-wave dependency chain cost more than L2 merging).
// => keep it simple: through-L2 strided, no nt, no LDS.
__global__ void __launch_bounds__(256)
coupling_kernel(const f32x4* __restrict__ z,   // 4 x float4 per row (16 fp32)
                WPtrs p,
                f32x4* __restrict__ out,
                int batch) {
    int idx = blockIdx.x * blockDim.x + threadIdx.x;
    if (idx >= batch) return;

    size_t base = (size_t)idx * 4;
    f32x4 r0 = z[base + 0];   // zl[0..3]
    f32x4 r1 = z[base + 1];   // zl[4..7]
    f32x4 r2 = z[base + 2];   // zr[0..3]
    f32x4 r3 = z[base + 3];   // zr[4..7]

    float zl[8] = { r0.x, r0.y, r0.z, r0.w, r1.x, r1.y, r1.z, r1.w };
    float zr[8] = { r2.x, r2.y, r2.z, r2.w, r3.x, r3.y, r3.z, r3.w };

    float log_s[8], bb[8];
    mlp8(p.logs, zl, log_s);
    mlp8(p.aff,  zl, bb);

    float yr[8];
    #pragma unroll
    for (int k = 0; k < 8; ++k)
        yr[k] = fmaf(__expf(log_s[k]), zr[k], bb[k]);

    f32x4 o2 = { yr[0], yr[1], yr[2], yr[3] };
    f32x4 o3 = { yr[4], yr[5], yr[6], yr[7] };

    out[base + 0] = r0;   // zl pass-through (bit-exact)
    out[base + 1] = r1;
    out[base + 2] = o2;
    out[base + 3] = o3;
}

extern "C" void kernel_launch(void* const* d_in, const int* in_sizes, int n_in,
                              void* d_out, int out_size, void* d_ws, size_t ws_size,
                              hipStream_t stream) {
    const int batch = in_sizes[0] / 16;

    WPtrs p;
    if (n_in >= 21) {
        // Lists flattened into 20 separate device arrays: pass pointers
        // directly as kernel args (no memcpy staging -> no blit dispatches).
        for (int i = 0; i < 5; ++i) {
            p.logs.w[i] = (const float*)d_in[1 + i];    // ws_logs[i]: 8x8
            p.logs.b[i] = (const float*)d_in[6 + i];    // bs_logs[i]: 8
            p.aff.w[i]  = (const float*)d_in[11 + i];   // ws_b[i]:    8x8
            p.aff.b[i]  = (const float*)d_in[16 + i];   // bs_b[i]:    8
        }
    } else {
        const float* wl = (const float*)d_in[1];
        const float* bl = (const float*)d_in[2];
        const float* wv = (const float*)d_in[3];
        const float* bv = (const float*)d_in[4];
        for (int i = 0; i < 5; ++i) {
            p.logs.w[i] = wl + i * 64;
            p.logs.b[i] = bl + i * 8;
            p.aff.w[i]  = wv + i * 64;
            p.aff.b[i]  = bv + i * 8;
        }
    }

    int threads = 256;
    int blocks = (batch + threads - 1) / threads;
    coupling_kernel<<<blocks, threads, 0, stream>>>(
        (const f32x4*)d_in[0], p, (f32x4*)d_out, batch);
}